// Round 6
// baseline (300.811 us; speedup 1.0000x reference)
//
#include <hip/hip_runtime.h>

// LinearConv2D: y[b, o=g*8+n, fi, t] =
//   sum_{d<8, fr<2, w<16} x[b, g*8+d, 2*fi+fr, 4*t+w] * wt[g*8+n, d, 2*fi+fr, w]
// Shapes: x[16,64,128,256] f32, wt[64,8,128,16] f32, out[16,64,64,61] f32.
//
// R6: R5 showed occupancy (TLP) is the dominant lever and the per-iteration
// stall is the weight scalar path (8 rows = 512B/iter can't fit in SGPRs ->
// serialized s_load + lgkmcnt(0) waits). Fix: stage the block's (g,fi)
// weight slice (8KB) into LDS once; in-loop weight reads become
// ds_read_b128 at wave-uniform addresses (same-address broadcast is
// conflict-free, ~120cy, finely pipelined). Restore R4's winning shape:
// 1 b per wave, 2048 blocks x 256 thr = 32 waves/CU, launch_bounds(256,8).
// 8KB LDS x 8 blocks/CU = 64KB (no LDS occupancy limit).

namespace {
constexpr int kB  = 16;
constexpr int kC  = 64;
constexpr int kF  = 128;
constexpr int kT  = 256;
constexpr int kG  = 8;
constexpr int kD  = 8;
constexpr int kN  = 8;
constexpr int kW  = 16;
constexpr int kKS = 4;
constexpr int kNT = 61;   // (256-16)/4 + 1
constexpr int kO  = 64;
constexpr int kFP = 64;   // (128-2)/2 + 1
}

__device__ __forceinline__ void fma_row(const float4& x0, const float4& x1,
                                        const float4& x2, const float4& x3,
                                        const float* wr,   // LDS, wave-uniform
                                        float& acc) {
  const float4 w0 = ((const float4*)wr)[0];
  const float4 w1 = ((const float4*)wr)[1];
  const float4 w2 = ((const float4*)wr)[2];
  const float4 w3 = ((const float4*)wr)[3];
  acc = fmaf(x0.x, w0.x, acc);
  acc = fmaf(x0.y, w0.y, acc);
  acc = fmaf(x0.z, w0.z, acc);
  acc = fmaf(x0.w, w0.w, acc);
  acc = fmaf(x1.x, w1.x, acc);
  acc = fmaf(x1.y, w1.y, acc);
  acc = fmaf(x1.z, w1.z, acc);
  acc = fmaf(x1.w, w1.w, acc);
  acc = fmaf(x2.x, w2.x, acc);
  acc = fmaf(x2.y, w2.y, acc);
  acc = fmaf(x2.z, w2.z, acc);
  acc = fmaf(x2.w, w2.w, acc);
  acc = fmaf(x3.x, w3.x, acc);
  acc = fmaf(x3.y, w3.y, acc);
  acc = fmaf(x3.z, w3.z, acc);
  acc = fmaf(x3.w, w3.w, acc);
}

__global__ __launch_bounds__(256, 8)
void lc2d_kernel(const float* __restrict__ x,
                 const float* __restrict__ wt,
                 float* __restrict__ out) {
  // LDS weight slice for this (g,fi): wlds[n*256 + d*32 + fr*16 + w]
  __shared__ float wlds[kN * kD * 2 * kW];   // 2048 floats = 8 KB

  const int tid  = threadIdx.x;
  const int lane = tid & 63;            // t
  const int wv   = tid >> 6;            // b within block (per-lane is fine)
  const int fi   = blockIdx.x;          // 0..63
  const int g    = blockIdx.y;          // 0..7
  const int b    = blockIdx.z * 4 + wv; // 0..15

  // ---- Stage weights: 2048 floats, 8 floats (2 float4) per thread. ----
  // chunk = n*8+d (0..63) is 32 contiguous floats in global at
  //   wt + (g*64 + chunk)*2048 + fi*32  (covering fr*16+w = 0..31).
  {
    const int chunk = tid >> 2;   // 0..63
    const int part  = tid & 3;    // 0..3  -> 8-float piece within chunk
    const float* gsrc =
        wt + ((size_t)(g * 64 + chunk)) * (kD * kF * kW / kD) /*2048*/ +
        fi * 32 + part * 8;
    const float4 q0 = ((const float4*)gsrc)[0];
    const float4 q1 = ((const float4*)gsrc)[1];
    float* dst = &wlds[chunk * 32 + part * 8];
    ((float4*)dst)[0] = q0;
    ((float4*)dst)[1] = q1;
  }
  __syncthreads();

  // Clamp inactive lanes so their (dead) loads stay in-bounds.
  const int tc   = (lane < kNT - 1) ? lane : (kNT - 1);
  const int tau0 = tc * kKS;            // max 240; +15 = 255 in bounds

  // x[b, g*8+d, 2*fi+fr, tau]; row(it=d*2+fr) offset = d*kF*kT + fr*kT
  const float* xbase = x + (((size_t)b * kC + g * kD) * kF + fi * 2) * kT + tau0;

  float a0 = 0.f, a1 = 0.f, a2 = 0.f, a3 = 0.f;
  float a4 = 0.f, a5 = 0.f, a6 = 0.f, a7 = 0.f;

  // Prime the x register double-buffer with row 0 (d=0, fr=0).
  float4 c0 = ((const float4*)xbase)[0];
  float4 c1 = ((const float4*)xbase)[1];
  float4 c2 = ((const float4*)xbase)[2];
  float4 c3 = ((const float4*)xbase)[3];

#pragma unroll 2
  for (int it = 0; it < 16; ++it) {
    // Prefetch next x row (it==15 reloads row 15 — harmless L1 hit).
    const int nx = (it < 15) ? it + 1 : 15;
    const float* xrn = xbase + ((size_t)(nx >> 1) * kF + (nx & 1)) * kT;
    float4 p0 = ((const float4*)xrn)[0];
    float4 p1 = ((const float4*)xrn)[1];
    float4 p2 = ((const float4*)xrn)[2];
    float4 p3 = ((const float4*)xrn)[3];

    // Weight rows for (d=it>>1, fr=it&1), n=0..7: LDS broadcast reads.
    // Base offset d*32 + fr*16; per-n stride 256 floats (1 KB imm offsets).
    const float* wr = &wlds[(it >> 1) * 32 + (it & 1) * 16];
    fma_row(c0, c1, c2, c3, wr + 0 * 256, a0);
    fma_row(c0, c1, c2, c3, wr + 1 * 256, a1);
    fma_row(c0, c1, c2, c3, wr + 2 * 256, a2);
    fma_row(c0, c1, c2, c3, wr + 3 * 256, a3);
    fma_row(c0, c1, c2, c3, wr + 4 * 256, a4);
    fma_row(c0, c1, c2, c3, wr + 5 * 256, a5);
    fma_row(c0, c1, c2, c3, wr + 6 * 256, a6);
    fma_row(c0, c1, c2, c3, wr + 7 * 256, a7);

    c0 = p0; c1 = p1; c2 = p2; c3 = p3;
  }

  if (lane < kNT) {
    float* ob = out + (((size_t)b * kO + g * kN) * kFP + fi) * (size_t)kNT + lane;
    const size_t s = (size_t)kFP * kNT;
    ob[0 * s] = a0;
    ob[1 * s] = a1;
    ob[2 * s] = a2;
    ob[3 * s] = a3;
    ob[4 * s] = a4;
    ob[5 * s] = a5;
    ob[6 * s] = a6;
    ob[7 * s] = a7;
  }
}

extern "C" void kernel_launch(void* const* d_in, const int* in_sizes, int n_in,
                              void* d_out, int out_size, void* d_ws, size_t ws_size,
                              hipStream_t stream) {
  const float* x  = (const float*)d_in[0];
  const float* wt = (const float*)d_in[1];
  float* out      = (float*)d_out;

  dim3 grid(kFP, kG, kB / 4);   // 64 x 8 x 4 = 2048 blocks of 256 threads
  lc2d_kernel<<<grid, 256, 0, stream>>>(x, wt, out);
}

// Round 7
// 209.191 us; speedup vs baseline: 1.4380x; 1.4380x over previous
//
#include <hip/hip_runtime.h>

// LinearConv2D: y[b, o=g*8+n, fi, t] =
//   sum_{d<8, fr<2, w<16} x[b, g*8+d, 2*fi+fr, 4*t+w] * wt[g*8+n, d, 2*fi+fr, w]
// Shapes: x[16,64,128,256] f32, wt[64,8,128,16] f32, out[16,64,64,61] f32.
//
// R7: ladder synthesis. R4 (1b/wave, 32 w/CU) ~= R5 (2b/wave, 16 w/CU): TLP
// saturated; the per-wave stall is the weight path — SMEM returns out-of-
// order on CDNA so each weight batch = full lgkmcnt(0) drain (~300-500cy),
// and ~102 SGPRs forbid in-wave lookahead. R6's LDS broadcast occupies the
// shared LDS data path (~12cy/read x 16k reads = ~80us) — dead end.
// Remaining lever: amortize each drain over more FMAs. Weights are
// b-independent -> 4 b PER WAVE: 512B weights/iter now feeds 512 FMAs
// (1024cy) vs ~800cy drain. Also: 512 blocks -> only 2 distinct 8KB weight
// slices per CU = 16KB -> fits sK$ (R4 had 64KB -> thrash).
//  - __launch_bounds__(256,2): ~180 VGPRs demanded, cap 256 -> NO spill
//    (spill tripwire: WRITE_SIZE must stay ~17MB).
//  - x register double-buffer per b (4 float4 x 4 b cur + same prefetch).
//  - (fi,g) pure blockIdx -> weights stay on the scalar pipe.

namespace {
constexpr int kB  = 16;
constexpr int kC  = 64;
constexpr int kF  = 128;
constexpr int kT  = 256;
constexpr int kG  = 8;
constexpr int kD  = 8;
constexpr int kN  = 8;
constexpr int kW  = 16;
constexpr int kKS = 4;
constexpr int kNT = 61;   // (256-16)/4 + 1
constexpr int kO  = 64;
constexpr int kFP = 64;   // (128-2)/2 + 1
constexpr int kWStride = kD * kF * kW;  // 16384: per-n weight stride (floats)
}

__global__ __launch_bounds__(256, 2)
void lc2d_kernel(const float* __restrict__ x,
                 const float* __restrict__ wt,
                 float* __restrict__ out) {
  const int lane = threadIdx.x & 63;     // t
  const int wq   = threadIdx.x >> 6;     // b-quad id (per-lane is fine)
  const int fi   = blockIdx.x;           // 0..63  (scalar!)
  const int g    = blockIdx.y;           // 0..7   (scalar!)

  // Clamp inactive lanes so their (dead) loads stay in-bounds.
  const int tc   = (lane < kNT - 1) ? lane : (kNT - 1);
  const int tau0 = tc * kKS;             // max 240; +15 = 255 in bounds

  // Per-b x bases: b = wq*4 + bb.
  const float* xb[4];
#pragma unroll
  for (int bb = 0; bb < 4; ++bb) {
    const int b = wq * 4 + bb;
    xb[bb] = x + (((size_t)b * kC + g * kD) * kF + fi * 2) * kT + tau0;
  }
  // wt[(g*8+n), d, 2*fi+fr, w] — depends ONLY on blockIdx -> s_load.
  const float* wbase = wt + ((size_t)(g * kN) * kD * kF + fi * 2) * (size_t)kW;

  float acc[4][kN];
#pragma unroll
  for (int bb = 0; bb < 4; ++bb)
#pragma unroll
    for (int n = 0; n < kN; ++n) acc[bb][n] = 0.f;

  // Prime the x register double-buffer with row 0 (d=0, fr=0).
  float4 cur[4][4];
#pragma unroll
  for (int bb = 0; bb < 4; ++bb)
#pragma unroll
    for (int q = 0; q < 4; ++q) cur[bb][q] = ((const float4*)xb[bb])[q];

#pragma unroll 2
  for (int it = 0; it < 16; ++it) {
    // Prefetch next x row for all 4 b (it==15 reloads row 15 — L1 hit).
    const int nx = (it < 15) ? it + 1 : 15;
    const size_t roff = ((size_t)(nx >> 1) * kF + (nx & 1)) * kT;
    float4 pre[4][4];
#pragma unroll
    for (int bb = 0; bb < 4; ++bb) {
      const float* xr = xb[bb] + roff;
#pragma unroll
      for (int q = 0; q < 4; ++q) pre[bb][q] = ((const float4*)xr)[q];
    }

    // Weight row for (d=it>>1, fr=it&1); scalar address -> s_load.
    const float* wr0 = wbase + (((size_t)(it >> 1) * kF + (it & 1))) * kW;
#pragma unroll
    for (int n = 0; n < kN; ++n) {
      const float* wr = wr0 + (size_t)n * kWStride;
      const float4 w0 = ((const float4*)wr)[0];
      const float4 w1 = ((const float4*)wr)[1];
      const float4 w2 = ((const float4*)wr)[2];
      const float4 w3 = ((const float4*)wr)[3];
#pragma unroll
      for (int bb = 0; bb < 4; ++bb) {
        float a = acc[bb][n];
        a = fmaf(cur[bb][0].x, w0.x, a);
        a = fmaf(cur[bb][0].y, w0.y, a);
        a = fmaf(cur[bb][0].z, w0.z, a);
        a = fmaf(cur[bb][0].w, w0.w, a);
        a = fmaf(cur[bb][1].x, w1.x, a);
        a = fmaf(cur[bb][1].y, w1.y, a);
        a = fmaf(cur[bb][1].z, w1.z, a);
        a = fmaf(cur[bb][1].w, w1.w, a);
        a = fmaf(cur[bb][2].x, w2.x, a);
        a = fmaf(cur[bb][2].y, w2.y, a);
        a = fmaf(cur[bb][2].z, w2.z, a);
        a = fmaf(cur[bb][2].w, w2.w, a);
        a = fmaf(cur[bb][3].x, w3.x, a);
        a = fmaf(cur[bb][3].y, w3.y, a);
        a = fmaf(cur[bb][3].z, w3.z, a);
        a = fmaf(cur[bb][3].w, w3.w, a);
        acc[bb][n] = a;
      }
    }

#pragma unroll
    for (int bb = 0; bb < 4; ++bb)
#pragma unroll
      for (int q = 0; q < 4; ++q) cur[bb][q] = pre[bb][q];
  }

  if (lane < kNT) {
    const size_t s = (size_t)kFP * kNT;
#pragma unroll
    for (int bb = 0; bb < 4; ++bb) {
      const int b = wq * 4 + bb;
      float* ob = out + (((size_t)b * kO + g * kN) * kFP + fi) * (size_t)kNT + lane;
#pragma unroll
      for (int n = 0; n < kN; ++n) ob[(size_t)n * s] = acc[bb][n];
    }
  }
}

extern "C" void kernel_launch(void* const* d_in, const int* in_sizes, int n_in,
                              void* d_out, int out_size, void* d_ws, size_t ws_size,
                              hipStream_t stream) {
  const float* x  = (const float*)d_in[0];
  const float* wt = (const float*)d_in[1];
  float* out      = (float*)d_out;

  dim3 grid(kFP, kG, 1);   // 64 x 8 = 512 blocks of 256 threads (16 b inside)
  lc2d_kernel<<<grid, 256, 0, stream>>>(x, wt, out);
}